// Round 5
// baseline (99.595 us; speedup 1.0000x reference)
//
#include <hip/hip_runtime.h>

#define NK 21      // classes
#define NC 256     // channels
#define NSRC 64    // source h/w
#define NOUT 256   // mask h/w
#define NB 8       // batch
#define NSL 64     // producer slices per image: one per source row (full width)
#define EPS 1e-6f

// Native LDS fp32 atomic add (ds_add_f32). Plain atomicAdd(float*) on LDS
// lowers to a CAS loop.
__device__ __forceinline__ void lds_fadd(float* p, float v) {
  __hip_atomic_fetch_add(p, v, __ATOMIC_RELAXED, __HIP_MEMORY_SCOPE_WORKGROUP);
}

__device__ __forceinline__ float d4(float s, float4 a, float4 w) {
  s = fmaf(a.x, w.x, s); s = fmaf(a.y, w.y, s);
  s = fmaf(a.z, w.z, s); return fmaf(a.w, w.w, s);
}

// Phase-2 contraction over a compile-time k range (static acc indices only;
// runtime-indexed ext-vector arrays go to scratch).
#define KLOOP(K0, K1)                                    \
  _Pragma("unroll")                                      \
  for (int k = (K0); k < (K1); ++k) {                    \
    const float4* wk = wb + k * 16;                      \
    float4 a = acc[k - (K0)];                            \
    _Pragma("unroll")                                    \
    for (int s = 0; s < 8; ++s) {                        \
      const float4 wv = wk[s];                           \
      a.x = d4(a.x, F[0][s], wv);                        \
      a.y = d4(a.y, F[1][s], wv);                        \
      a.z = d4(a.z, F[2][s], wv);                        \
      a.w = d4(a.w, F[3][s], wv);                        \
    }                                                    \
    acc[k - (K0)] = a;                                   \
  }

#define STORE_RED(K0, K1)                                \
  _Pragma("unroll")                                      \
  for (int k = (K0); k < (K1); ++k)                      \
    *(float4*)&Red[k * NC + c0] = acc[k - (K0)];

#define STORE_PSUM(K0, K1)                               \
  _Pragma("unroll")                                      \
  for (int k = (K0); k < (K1); ++k) {                    \
    const float4 r = *(const float4*)&Red[k * NC + c0];  \
    float4 a = acc[k - (K0)];                            \
    a.x += r.x; a.y += r.y; a.z += r.z; a.w += r.w;      \
    *(float4*)&dst[k * NC + c0] = a;                     \
  }

// ---------------------------------------------------------------------------
// Main kernel. Grid (64, NB): one full source row per 256-thread block.
// Wave w: column-half z = w&1, k-half kh = w>>1. Lane owns 4 channels
// (c0 = 4*lane) — halves the wave-uniform W-broadcast ds_read_b128 count
// (single LDS pipe per CU is the dominant modeled in-kernel cost).
// Block (0,0) also zeroes `out` for the final kernel's atomics (same-stream
// kernel-boundary coherence — the same guarantee psum relies on).
// NO fences/completion protocols: R2/R3 measured those at 45-60 us.
// ---------------------------------------------------------------------------
__global__ __launch_bounds__(256, 2)
void proto_main(const float* __restrict__ feats,
                const int* __restrict__ masks,
                float* __restrict__ psum,   // [B][NSL][K][C]
                float* __restrict__ pcnt,   // [B][NSL][K]
                float* __restrict__ out) {  // [K][C] zeroed here
  __shared__ __align__(16) float Wl[NK * 64];   // [k][src col] adjoint weights
  __shared__ __align__(16) float Red[NK * NC];  // z-half exchange buffer
  __shared__ int hist[NK];

  const int tid = threadIdx.x;
  const int r0 = blockIdx.x;   // source row 0..63
  const int bi = blockIdx.y;   // image
  const int w = tid >> 6;      // wave 0..3
  const int l = tid & 63;
  const int z = w & 1;         // column half 0/1
  const int kh = w >> 1;       // k-half: 0 -> k in [0,11), 1 -> [11,21)
  const int c0 = l << 2;       // 4-channel base

  // Zero the output accumulator for proto_final's atomics (21.5 KB).
  if (r0 == 0 && bi == 0) {
    float4* o4 = (float4*)out;
    for (int i = tid; i < NK * NC / 4; i += 256)
      o4[i] = make_float4(0.f, 0.f, 0.f, 0.f);
  }

  // ---- Phase 0a: prefetch the 8-row mask window (thread = column x) ----
  int ylo = 4 * r0 - 2; if (ylo < 0) ylo = 0;
  int yhi = 4 * r0 + 5; if (yhi > NOUT - 1) yhi = NOUT - 1;
  const int nr = yhi - ylo + 1;   // 6..8
  const int x = tid;              // fixed output column per thread
  int lab[8];
#pragma unroll
  for (int j = 0; j < 8; ++j)
    lab[j] = (j < nr) ? masks[((size_t)bi * NOUT + ylo + j) * NOUT + x] : NK;

  // ---- Phase 0b: feats prefetch: channels c0..c0+3, cols [32z, 32z+32) ----
  const float* fb = feats + (((size_t)(bi * NC + c0)) << 12) +
                    (size_t)r0 * 64 + 32 * z;
  float4 F[4][8];
#pragma unroll
  for (int ch = 0; ch < 4; ++ch) {
    const float4* fp = (const float4*)(fb + ((size_t)ch << 12));
#pragma unroll
    for (int s = 0; s < 8; ++s) F[ch][s] = fp[s];
  }

  for (int i = tid; i < NK * 64; i += 256) Wl[i] = 0.f;
  if (tid < NK) hist[tid] = 0;
  __syncthreads();

  // ---- Phase 1: bilinear-adjoint weights W[21][64] in LDS ----
  const int rx = x >> 2, px = x & 3;
  const int j0x = (px < 2) ? rx - 1 : rx;
  const float fx = (px == 0) ? 0.625f : (px == 1) ? 0.875f
                 : (px == 2) ? 0.125f : 0.375f;
  const int cx0 = (j0x < 0) ? 0 : j0x;
  const int cx1 = (j0x + 1 > NSRC - 1) ? NSRC - 1 : j0x + 1;
  const float wx0 = 1.f - fx, wx1 = fx;

#pragma unroll
  for (int j = 0; j < 8; ++j) {
    if (j < nr) {                 // wave-uniform
      const int y = ylo + j;
      const int lbl = lab[j];
      if ((unsigned)lbl < NK) {
        const int ry = y >> 2, py = y & 3;
        const int j0y = (py < 2) ? ry - 1 : ry;
        const float fy = (py == 0) ? 0.625f : (py == 1) ? 0.875f
                       : (py == 2) ? 0.125f : 0.375f;
        const int ry0 = (j0y < 0) ? 0 : j0y;
        const int ry1 = (j0y + 1 > NSRC - 1) ? NSRC - 1 : j0y + 1;
        float* Wk = &Wl[lbl << 6];
        if (ry0 == r0) {          // wave-uniform row predicate
          lds_fadd(&Wk[cx0], (1.f - fy) * wx0);
          lds_fadd(&Wk[cx1], (1.f - fy) * wx1);
        }
        if (ry1 == r0) {          // wave-uniform row predicate
          lds_fadd(&Wk[cx0], fy * wx0);
          lds_fadd(&Wk[cx1], fy * wx1);
        }
        if ((unsigned)(y - 4 * r0) < 4u)   // ownership rows 4r0..4r0+3
          atomicAdd(&hist[lbl], 1);        // int: native ds_add
      }
    }
  }
  __syncthreads();

  // ---- Phase 2: acc[k][4ch] = sum_s W[k][32z+s] * F[ch][s], k in my half ----
  float4 acc[11];
#pragma unroll
  for (int k = 0; k < 11; ++k) acc[k] = make_float4(0.f, 0.f, 0.f, 0.f);

  const float4* wb = (const float4*)&Wl[z * 32];  // k stride = 16 float4
  if (kh == 0) { KLOOP(0, 11) } else { KLOOP(11, 21) }

  // ---- z-half pair reduction (z=1 waves -> z=0 waves, same k-half) ----
  if (z == 1) {
    if (kh == 0) { STORE_RED(0, 11) } else { STORE_RED(11, 21) }
  }
  __syncthreads();
  if (z == 0) {
    float* dst = psum + ((size_t)(bi * NSL + r0) * NK) * NC;
    if (kh == 0) { STORE_PSUM(0, 11) } else { STORE_PSUM(11, 21) }
  }
  if (tid < NK) pcnt[(size_t)(bi * NSL + r0) * NK + tid] = (float)hist[tid];
}

// ---------------------------------------------------------------------------
// Single merged finalize. Grid (NK, NB) = 168 blocks; block (k,b) reduces all
// 64 row-slices (64 coalesced 1-KB rows, deep MLP), normalizes per-image,
// and atomicAdds the result into out[k][:]. Only 8 same-address adds per
// location (43K atomics total) — no fences, no completion protocol.
// ---------------------------------------------------------------------------
__global__ __launch_bounds__(256)
void proto_final(const float* __restrict__ psum,
                 const float* __restrict__ pcnt,
                 float* __restrict__ out) {  // [K][C], zeroed by proto_main
  const int k = blockIdx.x;   // 0..20
  const int b = blockIdx.y;   // 0..7
  const int c = threadIdx.x;  // 0..255

  float s = 0.f, cnt = 0.f;
#pragma unroll 8
  for (int j = 0; j < NSL; ++j) {
    s += psum[((size_t)(b * NSL + j) * NK + k) * NC + c];  // coalesced
    cnt += pcnt[(size_t)(b * NSL + j) * NK + k];           // uniform/broadcast
  }
  atomicAdd(&out[(size_t)k * NC + c], s / (cnt + EPS) * 0.125f);
}

extern "C" void kernel_launch(void* const* d_in, const int* in_sizes, int n_in,
                              void* d_out, int out_size, void* d_ws, size_t ws_size,
                              hipStream_t stream) {
  const float* feats = (const float*)d_in[0];
  const int* masks = (const int*)d_in[1];
  float* out = (float*)d_out;

  // ws: psum [8][64][21][256] (11.0 MB) | pcnt [8][64][21] (43 KB)
  // All regions fully overwritten before read; no memset needed.
  float* psum = (float*)d_ws;
  float* pcnt = psum + (size_t)NB * NSL * NK * NC;

  proto_main<<<dim3(64, NB), 256, 0, stream>>>(feats, masks, psum, pcnt, out);
  proto_final<<<dim3(NK, NB), 256, 0, stream>>>(psum, pcnt, out);
}

// Round 6
// 98.625 us; speedup vs baseline: 1.0098x; 1.0098x over previous
//
#include <hip/hip_runtime.h>

#define NK 21      // classes
#define NC 256     // channels
#define NSRC 64    // source h/w
#define NOUT 256   // mask h/w
#define NB 8       // batch
#define NSL 64     // producer slices per image: one per source row (full width)
#define NG 8       // finalA slice-groups (NSL/8 per group)
#define EPS 1e-6f

// Native LDS fp32 atomic add (ds_add_f32). Plain atomicAdd(float*) on LDS
// lowers to a CAS loop.
__device__ __forceinline__ void lds_fadd(float* p, float v) {
  __hip_atomic_fetch_add(p, v, __ATOMIC_RELAXED, __HIP_MEMORY_SCOPE_WORKGROUP);
}

__device__ __forceinline__ float d4(float s, float4 a, float4 w) {
  s = fmaf(a.x, w.x, s); s = fmaf(a.y, w.y, s);
  s = fmaf(a.z, w.z, s); return fmaf(a.w, w.w, s);
}

// Phase-2 contraction over a compile-time k range (static acc indices only;
// runtime-indexed ext-vector arrays go to scratch).
#define KLOOP(K0, K1)                                    \
  _Pragma("unroll")                                      \
  for (int k = (K0); k < (K1); ++k) {                    \
    const float4* wk = wb + k * 16;                      \
    float4 a = acc[k - (K0)];                            \
    _Pragma("unroll")                                    \
    for (int s = 0; s < 8; ++s) {                        \
      const float4 wv = wk[s];                           \
      a.x = d4(a.x, F[0][s], wv);                        \
      a.y = d4(a.y, F[1][s], wv);                        \
      a.z = d4(a.z, F[2][s], wv);                        \
      a.w = d4(a.w, F[3][s], wv);                        \
    }                                                    \
    acc[k - (K0)] = a;                                   \
  }

#define STORE_RED(K0, K1)                                \
  _Pragma("unroll")                                      \
  for (int k = (K0); k < (K1); ++k)                      \
    *(float4*)&Red[k * NC + c0] = acc[k - (K0)];

#define STORE_PSUM(K0, K1)                               \
  _Pragma("unroll")                                      \
  for (int k = (K0); k < (K1); ++k) {                    \
    const float4 r = *(const float4*)&Red[k * NC + c0];  \
    float4 a = acc[k - (K0)];                            \
    a.x += r.x; a.y += r.y; a.z += r.z; a.w += r.w;      \
    *(float4*)&dst[k * NC + c0] = a;                     \
  }

// ---------------------------------------------------------------------------
// Main kernel. Grid (64, NB): one full source row per 256-thread block.
// Wave w: column-half z = w&1, k-half kh = w>>1. Lane owns 4 channels
// (c0 = 4*lane). The wave-uniform W-broadcast ds_read_b128 count per block
// (the modeled dominant cost: single LDS pipe per CU) is half of R1's.
// NO global atomics, NO fences — R2/R3 measured the completion-protocol
// cost at 45-60 us on this chip; three plain launches are far cheaper.
// ---------------------------------------------------------------------------
__global__ __launch_bounds__(256, 2)
void proto_main(const float* __restrict__ feats,
                const int* __restrict__ masks,
                float* __restrict__ psum,   // [B][NSL][K][C]
                float* __restrict__ pcnt) { // [B][NSL][K]
  __shared__ __align__(16) float Wl[NK * 64];   // [k][src col] adjoint weights
  __shared__ __align__(16) float Red[NK * NC];  // z-half exchange buffer
  __shared__ int hist[NK];

  const int tid = threadIdx.x;
  const int r0 = blockIdx.x;   // source row 0..63
  const int bi = blockIdx.y;   // image
  const int w = tid >> 6;      // wave 0..3
  const int l = tid & 63;
  const int z = w & 1;         // column half 0/1
  const int kh = w >> 1;       // k-half: 0 -> k in [0,11), 1 -> [11,21)
  const int c0 = l << 2;       // 4-channel base

  // ---- Phase 0a: prefetch the 8-row mask window (thread = column x) ----
  int ylo = 4 * r0 - 2; if (ylo < 0) ylo = 0;
  int yhi = 4 * r0 + 5; if (yhi > NOUT - 1) yhi = NOUT - 1;
  const int nr = yhi - ylo + 1;   // 6..8
  const int x = tid;              // fixed output column per thread
  int lab[8];
#pragma unroll
  for (int j = 0; j < 8; ++j)
    lab[j] = (j < nr) ? masks[((size_t)bi * NOUT + ylo + j) * NOUT + x] : NK;

  // ---- Phase 0b: feats prefetch: channels c0..c0+3, cols [32z, 32z+32) ----
  const float* fb = feats + (((size_t)(bi * NC + c0)) << 12) +
                    (size_t)r0 * 64 + 32 * z;
  float4 F[4][8];
#pragma unroll
  for (int ch = 0; ch < 4; ++ch) {
    const float4* fp = (const float4*)(fb + ((size_t)ch << 12));
#pragma unroll
    for (int s = 0; s < 8; ++s) F[ch][s] = fp[s];
  }

  for (int i = tid; i < NK * 64; i += 256) Wl[i] = 0.f;
  if (tid < NK) hist[tid] = 0;
  __syncthreads();

  // ---- Phase 1: bilinear-adjoint weights W[21][64] in LDS ----
  const int rx = x >> 2, px = x & 3;
  const int j0x = (px < 2) ? rx - 1 : rx;
  const float fx = (px == 0) ? 0.625f : (px == 1) ? 0.875f
                 : (px == 2) ? 0.125f : 0.375f;
  const int cx0 = (j0x < 0) ? 0 : j0x;
  const int cx1 = (j0x + 1 > NSRC - 1) ? NSRC - 1 : j0x + 1;
  const float wx0 = 1.f - fx, wx1 = fx;

#pragma unroll
  for (int j = 0; j < 8; ++j) {
    if (j < nr) {                 // wave-uniform
      const int y = ylo + j;
      const int lbl = lab[j];
      if ((unsigned)lbl < NK) {
        const int ry = y >> 2, py = y & 3;
        const int j0y = (py < 2) ? ry - 1 : ry;
        const float fy = (py == 0) ? 0.625f : (py == 1) ? 0.875f
                       : (py == 2) ? 0.125f : 0.375f;
        const int ry0 = (j0y < 0) ? 0 : j0y;
        const int ry1 = (j0y + 1 > NSRC - 1) ? NSRC - 1 : j0y + 1;
        float* Wk = &Wl[lbl << 6];
        if (ry0 == r0) {          // wave-uniform row predicate
          lds_fadd(&Wk[cx0], (1.f - fy) * wx0);
          lds_fadd(&Wk[cx1], (1.f - fy) * wx1);
        }
        if (ry1 == r0) {          // wave-uniform row predicate
          lds_fadd(&Wk[cx0], fy * wx0);
          lds_fadd(&Wk[cx1], fy * wx1);
        }
        if ((unsigned)(y - 4 * r0) < 4u)   // ownership rows 4r0..4r0+3
          atomicAdd(&hist[lbl], 1);        // int: native ds_add
      }
    }
  }
  __syncthreads();

  // ---- Phase 2: acc[k][4ch] = sum_s W[k][32z+s] * F[ch][s], k in my half ----
  float4 acc[11];
#pragma unroll
  for (int k = 0; k < 11; ++k) acc[k] = make_float4(0.f, 0.f, 0.f, 0.f);

  const float4* wb = (const float4*)&Wl[z * 32];  // k stride = 16 float4
  if (kh == 0) { KLOOP(0, 11) } else { KLOOP(11, 21) }

  // ---- z-half pair reduction (z=1 waves -> z=0 waves, same k-half) ----
  if (z == 1) {
    if (kh == 0) { STORE_RED(0, 11) } else { STORE_RED(11, 21) }
  }
  __syncthreads();
  if (z == 0) {
    float* dst = psum + ((size_t)(bi * NSL + r0) * NK) * NC;
    if (kh == 0) { STORE_PSUM(0, 11) } else { STORE_PSUM(11, 21) }
  }
  if (tid < NK) pcnt[(size_t)(bi * NSL + r0) * NK + tid] = (float)hist[tid];
}

// ---------------------------------------------------------------------------
// Finalize A: grid (NK, NB, NG) = 1344 blocks; each reduces 8 row-slices.
// Plain loads/stores only.
// ---------------------------------------------------------------------------
__global__ __launch_bounds__(256)
void proto_finalA(const float* __restrict__ psum,
                  const float* __restrict__ pcnt,
                  float* __restrict__ psum2,   // [B][NG][K][C]
                  float* __restrict__ pcnt2) { // [B][NG][K]
  const int k = blockIdx.x;   // 0..20
  const int b = blockIdx.y;   // 0..7
  const int g = blockIdx.z;   // 0..7
  const int c = threadIdx.x;  // 0..255
  const int sl0 = g * (NSL / NG);
  float s = 0.f, cnt = 0.f;
#pragma unroll
  for (int j = 0; j < NSL / NG; ++j) {
    s += psum[((size_t)(b * NSL + sl0 + j) * NK + k) * NC + c];  // coalesced
    cnt += pcnt[(size_t)(b * NSL + sl0 + j) * NK + k];           // uniform
  }
  psum2[((size_t)(b * NG + g) * NK + k) * NC + c] = s;
  if (c == 0) pcnt2[(size_t)(b * NG + g) * NK + k] = cnt;
}

// ---------------------------------------------------------------------------
// Finalize B: grid (NK); L2-hot 1.4 MB.
// out[k][c] = (1/8) sum_b [sum_g psum2] / (sum_g pcnt2 + eps)
// ---------------------------------------------------------------------------
__global__ __launch_bounds__(256)
void proto_finalB(const float* __restrict__ psum2,
                  const float* __restrict__ pcnt2,
                  float* __restrict__ out) {
  const int k = blockIdx.x;
  const int c = threadIdx.x;
  float a = 0.f;
#pragma unroll
  for (int b = 0; b < NB; ++b) {
    float s = 0.f, cnt = 0.f;
#pragma unroll
    for (int g = 0; g < NG; ++g) {
      s += psum2[((size_t)(b * NG + g) * NK + k) * NC + c];
      cnt += pcnt2[(size_t)(b * NG + g) * NK + k];
    }
    a += s / (cnt + EPS);
  }
  out[(size_t)k * NC + c] = a * 0.125f;
}

extern "C" void kernel_launch(void* const* d_in, const int* in_sizes, int n_in,
                              void* d_out, int out_size, void* d_ws, size_t ws_size,
                              hipStream_t stream) {
  const float* feats = (const float*)d_in[0];
  const int* masks = (const int*)d_in[1];
  float* out = (float*)d_out;

  // ws: psum [8][64][21][256] (11.0 MB) | pcnt [8][64][21] (43 KB)
  //   | psum2 [8][8][21][256] (1.38 MB) | pcnt2 [8][8][21] (5.4 KB)
  // All regions fully overwritten before read; no memset needed.
  float* psum = (float*)d_ws;
  float* pcnt = psum + (size_t)NB * NSL * NK * NC;
  float* psum2 = pcnt + (size_t)NB * NSL * NK;
  float* pcnt2 = psum2 + (size_t)NB * NG * NK * NC;

  proto_main<<<dim3(64, NB), 256, 0, stream>>>(feats, masks, psum, pcnt);
  proto_finalA<<<dim3(NK, NB, NG), 256, 0, stream>>>(psum, pcnt, psum2, pcnt2);
  proto_finalB<<<dim3(NK), 256, 0, stream>>>(psum2, pcnt2, out);
}